// Round 1
// baseline (1301.980 us; speedup 1.0000x reference)
//
#include <hip/hip_runtime.h>
#include <hip/hip_bf16.h>

#define HD 128
#define LN_EPS 1e-5f

// ---------- block-wide (128 threads = 2 waves) dual reduction ----------
__device__ __forceinline__ void block_reduce2_128(float& a, float& b) {
  #pragma unroll
  for (int off = 32; off > 0; off >>= 1) {
    a += __shfl_down(a, off);
    b += __shfl_down(b, off);
  }
  __shared__ float pa[2], pb[2];
  int w = threadIdx.x >> 6;
  if ((threadIdx.x & 63) == 0) { pa[w] = a; pb[w] = b; }
  __syncthreads();
  a = pa[0] + pa[1];
  b = pb[0] + pb[1];
}

// ---------- CSR build ----------
__global__ void init_counts(int* __restrict__ counts, int N) {
  int i = blockIdx.x * blockDim.x + threadIdx.x;
  if (i < N) counts[i] = 0;
}

__global__ void count_deg(const int* __restrict__ dst, int* __restrict__ counts, int E) {
  int e = blockIdx.x * blockDim.x + threadIdx.x;
  if (e < E) atomicAdd(&counts[dst[e]], 1);
}

__global__ __launch_bounds__(1024) void scan1(const int* __restrict__ counts,
                                              int* __restrict__ row_ptr,
                                              int* __restrict__ bsums, int N) {
  __shared__ int s[1024];
  int t = threadIdx.x;
  int i = blockIdx.x * 1024 + t;
  int v = (i < N) ? counts[i] : 0;
  s[t] = v;
  __syncthreads();
  for (int off = 1; off < 1024; off <<= 1) {
    int u = (t >= off) ? s[t - off] : 0;
    __syncthreads();
    s[t] += u;
    __syncthreads();
  }
  if (i < N) row_ptr[i + 1] = s[t];          // inclusive scan within block
  if (t == 1023) bsums[blockIdx.x] = s[1023];
  if (i == 0) row_ptr[0] = 0;
}

__global__ __launch_bounds__(1024) void scan2(int* __restrict__ bsums, int nb) {
  __shared__ int s[1024];
  int t = threadIdx.x;
  int v = (t < nb) ? bsums[t] : 0;
  s[t] = v;
  __syncthreads();
  for (int off = 1; off < 1024; off <<= 1) {
    int u = (t >= off) ? s[t - off] : 0;
    __syncthreads();
    s[t] += u;
    __syncthreads();
  }
  if (t < nb) bsums[t] = (t == 0) ? 0 : s[t - 1];  // exclusive block offsets
}

__global__ void scan3(int* __restrict__ row_ptr, const int* __restrict__ bsums, int N) {
  int i = blockIdx.x * blockDim.x + threadIdx.x;
  if (i < N) row_ptr[i + 1] += bsums[i >> 10];
}

__global__ void copy_fill(int* __restrict__ fill, const int* __restrict__ row_ptr, int N) {
  int i = blockIdx.x * blockDim.x + threadIdx.x;
  if (i < N) fill[i] = row_ptr[i];
}

__global__ void fill_col(const int* __restrict__ src, const int* __restrict__ dst,
                         int* __restrict__ fill, int* __restrict__ col, int E) {
  int e = blockIdx.x * blockDim.x + threadIdx.x;
  if (e < E) {
    int pos = atomicAdd(&fill[dst[e]], 1);
    col[pos] = src[e];
  }
}

__global__ void compute_dinv(const int* __restrict__ counts, float* __restrict__ dinv, int N) {
  int i = blockIdx.x * blockDim.x + threadIdx.x;
  if (i < N) dinv[i] = rsqrtf((float)(counts[i] + 1));   // +1 self loop
}

// ---------- node encoder: Linear(7->128) + LN + ReLU ----------
__global__ __launch_bounds__(128) void encoder(const float* __restrict__ nf,
                                               const float* __restrict__ enc_w,
                                               const float* __restrict__ enc_b,
                                               const float* __restrict__ g,
                                               const float* __restrict__ bt,
                                               float* __restrict__ x, int N) {
  int n = blockIdx.x;
  int t = threadIdx.x;
  __shared__ float f[7];
  if (t < 7) f[t] = nf[(size_t)n * 7 + t];
  __syncthreads();
  float v = enc_b[t];
  #pragma unroll
  for (int k = 0; k < 7; k++) v = fmaf(f[k], enc_w[k * HD + t], v);
  float s1 = v, s2 = v * v;
  block_reduce2_128(s1, s2);
  float mu = s1 * (1.f / HD);
  float var = s2 * (1.f / HD) - mu * mu;
  float o = (v - mu) * rsqrtf(var + LN_EPS) * g[t] + bt[t];
  x[(size_t)n * HD + t] = fmaxf(o, 0.f);
}

// ---------- GEMM: out[N,128] = in[N,128] @ W[128,128] ----------
__global__ __launch_bounds__(256) void gemm128(const float* __restrict__ in,
                                               const float* __restrict__ W,
                                               float* __restrict__ out, int N) {
  __shared__ float Ws[64 * HD];   // 32 KB (K-chunk of 64)
  __shared__ float xs[32 * HD];   // 16 KB
  int t = threadIdx.x;
  int node0 = blockIdx.x * 32;
  for (int i = t; i < 32 * (HD / 4); i += 256) {
    int node = node0 + (i >> 5);
    float4 v = make_float4(0.f, 0.f, 0.f, 0.f);
    if (node < N) v = reinterpret_cast<const float4*>(in)[(size_t)node * (HD / 4) + (i & 31)];
    reinterpret_cast<float4*>(xs)[i] = v;
  }
  int cg = t & 31;   // channels 4*cg..4*cg+3
  int ng = t >> 5;   // nodes   node0+4*ng..+3
  float acc[4][4] = {{0.f}};
  for (int k0 = 0; k0 < HD; k0 += 64) {
    __syncthreads();
    for (int i = t; i < 64 * (HD / 4); i += 256)
      reinterpret_cast<float4*>(Ws)[i] =
          reinterpret_cast<const float4*>(W + (size_t)k0 * HD)[i];
    __syncthreads();
    for (int k = 0; k < 64; k += 4) {
      float4 xv[4];
      #pragma unroll
      for (int nn = 0; nn < 4; nn++)
        xv[nn] = reinterpret_cast<const float4*>(xs + (ng * 4 + nn) * HD)[(k0 + k) >> 2];
      #pragma unroll
      for (int j = 0; j < 4; j++) {
        float4 wv = reinterpret_cast<const float4*>(Ws + (k + j) * HD)[cg];
        #pragma unroll
        for (int nn = 0; nn < 4; nn++) {
          float xe = (j == 0) ? xv[nn].x : (j == 1) ? xv[nn].y : (j == 2) ? xv[nn].z : xv[nn].w;
          acc[nn][0] = fmaf(xe, wv.x, acc[nn][0]);
          acc[nn][1] = fmaf(xe, wv.y, acc[nn][1]);
          acc[nn][2] = fmaf(xe, wv.z, acc[nn][2]);
          acc[nn][3] = fmaf(xe, wv.w, acc[nn][3]);
        }
      }
    }
  }
  #pragma unroll
  for (int nn = 0; nn < 4; nn++) {
    int node = node0 + ng * 4 + nn;
    if (node < N)
      reinterpret_cast<float4*>(out)[(size_t)node * (HD / 4) + cg] =
          make_float4(acc[nn][0], acc[nn][1], acc[nn][2], acc[nn][3]);
  }
}

// ---------- fused gather-aggregate + bias + LN + ReLU + residual ----------
__global__ __launch_bounds__(128) void aggregate(const float* __restrict__ h,
                                                 const float* __restrict__ xin,
                                                 const int* __restrict__ row_ptr,
                                                 const int* __restrict__ col,
                                                 const float* __restrict__ dinv,
                                                 const float* __restrict__ conv_b,
                                                 const float* __restrict__ g,
                                                 const float* __restrict__ bt,
                                                 float* __restrict__ xout, int N) {
  int n = blockIdx.x;
  int t = threadIdx.x;
  int beg = row_ptr[n], end = row_ptr[n + 1];
  float dn = dinv[n];
  float acc = dn * h[(size_t)n * HD + t];   // self loop (outer dn applied later)
  __shared__ int   scol[128];
  __shared__ float sdv[128];
  for (int base = beg; base < end; base += 128) {
    int m = min(128, end - base);
    if (t < m) {
      int s = col[base + t];
      scol[t] = s;
      sdv[t] = dinv[s];
    }
    __syncthreads();
    int j = 0;
    for (; j + 4 <= m; j += 4) {
      float a0 = h[(size_t)scol[j + 0] * HD + t];
      float a1 = h[(size_t)scol[j + 1] * HD + t];
      float a2 = h[(size_t)scol[j + 2] * HD + t];
      float a3 = h[(size_t)scol[j + 3] * HD + t];
      acc = fmaf(sdv[j + 0], a0, acc);
      acc = fmaf(sdv[j + 1], a1, acc);
      acc = fmaf(sdv[j + 2], a2, acc);
      acc = fmaf(sdv[j + 3], a3, acc);
    }
    for (; j < m; j++) acc = fmaf(sdv[j], h[(size_t)scol[j] * HD + t], acc);
    __syncthreads();
  }
  float v = dn * acc + conv_b[t];
  float s1 = v, s2 = v * v;
  block_reduce2_128(s1, s2);
  float mu = s1 * (1.f / HD);
  float var = s2 * (1.f / HD) - mu * mu;
  float o = (v - mu) * rsqrtf(var + LN_EPS) * g[t] + bt[t];
  xout[(size_t)n * HD + t] = fmaxf(o, 0.f) + xin[(size_t)n * HD + t];
}

// ---------- edge scoring: logit = relu(P[src]+Q[dst]+b1) . W2 + b2 ----------
__global__ __launch_bounds__(256) void edge_mlp(const float* __restrict__ P,
                                                const float* __restrict__ Q,
                                                const int* __restrict__ src,
                                                const int* __restrict__ dst,
                                                const float* __restrict__ b1,
                                                const float* __restrict__ w2,
                                                const float* __restrict__ b2,
                                                float* __restrict__ out, int E) {
  int e = (blockIdx.x * 256 + threadIdx.x) >> 6;   // one wave per edge
  int lane = threadIdx.x & 63;
  if (e >= E) return;
  int s = src[e], d = dst[e];
  float2 p = reinterpret_cast<const float2*>(P + (size_t)s * HD)[lane];
  float2 q = reinterpret_cast<const float2*>(Q + (size_t)d * HD)[lane];
  float2 bb = reinterpret_cast<const float2*>(b1)[lane];
  float2 w = reinterpret_cast<const float2*>(w2)[lane];
  float h0 = fmaxf(p.x + q.x + bb.x, 0.f);
  float h1 = fmaxf(p.y + q.y + bb.y, 0.f);
  float acc = fmaf(h0, w.x, h1 * w.y);
  #pragma unroll
  for (int off = 32; off > 0; off >>= 1) acc += __shfl_down(acc, off);
  if (lane == 0) out[e] = acc + b2[0];
}

extern "C" void kernel_launch(void* const* d_in, const int* in_sizes, int n_in,
                              void* d_out, int out_size, void* d_ws, size_t ws_size,
                              hipStream_t stream) {
  const float* node_features = (const float*)d_in[0];
  const int*   edge_index    = (const int*)d_in[1];
  // d_in[2] = edge_attr (unused by the reference)
  const float* enc_w    = (const float*)d_in[3];
  const float* enc_b    = (const float*)d_in[4];
  const float* enc_ln_g = (const float*)d_in[5];
  const float* enc_ln_b = (const float*)d_in[6];
  const float* conv_w   = (const float*)d_in[7];
  const float* conv_b   = (const float*)d_in[8];
  const float* ln_g     = (const float*)d_in[9];
  const float* ln_b     = (const float*)d_in[10];
  const float* mlp_w1   = (const float*)d_in[11];
  const float* mlp_b1   = (const float*)d_in[12];
  const float* mlp_w2   = (const float*)d_in[13];
  const float* mlp_b2   = (const float*)d_in[14];

  const int N = in_sizes[0] / 7;
  const int E = in_sizes[1] / 2;
  const int* src = edge_index;       // edge_index[0]
  const int* dst = edge_index + E;   // edge_index[1]

  // workspace layout (~110 MB)
  char* ws = (char*)d_ws;
  float* x    = (float*)ws;  ws += (size_t)N * HD * 4;
  float* h    = (float*)ws;  ws += (size_t)N * HD * 4;
  float* dinv = (float*)ws;  ws += (size_t)N * 4;
  int* counts = (int*)ws;    ws += (size_t)N * 4;
  int* fill   = (int*)ws;    ws += (size_t)N * 4;
  int* col    = (int*)ws;    ws += (size_t)E * 4;
  int* rowp   = (int*)ws;    ws += (size_t)(N + 1) * 4;
  int* bsums  = (int*)ws;    ws += 4096;

  float* out_x      = (float*)d_out;
  float* out_logits = out_x + (size_t)N * HD;

  const int T = 256;
  int nblk = (N + 1023) / 1024;

  // CSR (by dst) + degrees
  init_counts<<<(N + T - 1) / T, T, 0, stream>>>(counts, N);
  count_deg<<<(E + T - 1) / T, T, 0, stream>>>(dst, counts, E);
  scan1<<<nblk, 1024, 0, stream>>>(counts, rowp, bsums, N);
  scan2<<<1, 1024, 0, stream>>>(bsums, nblk);
  scan3<<<(N + T - 1) / T, T, 0, stream>>>(rowp, bsums, N);
  copy_fill<<<(N + T - 1) / T, T, 0, stream>>>(fill, rowp, N);
  fill_col<<<(E + T - 1) / T, T, 0, stream>>>(src, dst, fill, col, E);
  compute_dinv<<<(N + T - 1) / T, T, 0, stream>>>(counts, dinv, N);

  // encoder
  encoder<<<N, 128, 0, stream>>>(node_features, enc_w, enc_b, enc_ln_g, enc_ln_b, x, N);

  // GCN layers
  int gblk = (N + 31) / 32;
  for (int l = 0; l < 3; l++) {
    gemm128<<<gblk, 256, 0, stream>>>(x, conv_w + (size_t)l * HD * HD, h, N);
    float* xout = (l == 2) ? out_x : x;
    aggregate<<<N, 128, 0, stream>>>(h, x, rowp, col, dinv,
                                     conv_b + l * HD, ln_g + l * HD, ln_b + l * HD,
                                     xout, N);
  }

  // edge MLP factored: P = x@W1_top, Q = x@W1_bot
  gemm128<<<gblk, 256, 0, stream>>>(out_x, mlp_w1, h, N);              // P
  gemm128<<<gblk, 256, 0, stream>>>(out_x, mlp_w1 + HD * HD, x, N);    // Q
  edge_mlp<<<(E + 3) / 4, 256, 0, stream>>>(h, x, src, dst, mlp_b1, mlp_w2, mlp_b2,
                                            out_logits, E);
}

// Round 2
// 926.547 us; speedup vs baseline: 1.4052x; 1.4052x over previous
//
#include <hip/hip_runtime.h>
#include <hip/hip_bf16.h>

#define HD 128
#define LN_EPS 1e-5f
typedef unsigned int u32;

// ---------- bf16 pack/unpack (bit-level, round-to-nearest-even) ----------
__device__ __forceinline__ u32 f2bf(float f) {
  u32 u = __float_as_uint(f);
  return (u + 0x7FFFu + ((u >> 16) & 1u)) >> 16;
}
__device__ __forceinline__ float bf_lo(u32 p) { return __uint_as_float(p << 16); }
__device__ __forceinline__ float bf_hi(u32 p) { return __uint_as_float(p & 0xFFFF0000u); }
__device__ __forceinline__ u32 pack2(float a, float b) { return f2bf(a) | (f2bf(b) << 16); }

// ---------- block-wide (128 threads = 2 waves) dual reduction ----------
__device__ __forceinline__ void block_reduce2_128(float& a, float& b) {
  #pragma unroll
  for (int off = 32; off > 0; off >>= 1) {
    a += __shfl_down(a, off);
    b += __shfl_down(b, off);
  }
  __shared__ float pa[2], pb[2];
  int w = threadIdx.x >> 6;
  if ((threadIdx.x & 63) == 0) { pa[w] = a; pb[w] = b; }
  __syncthreads();
  a = pa[0] + pa[1];
  b = pb[0] + pb[1];
}

// ---------- CSR build ----------
__global__ void init_counts(int* __restrict__ counts, int N) {
  int i = blockIdx.x * blockDim.x + threadIdx.x;
  if (i < N) counts[i] = 0;
}

__global__ void count_deg(const int* __restrict__ dst, int* __restrict__ counts, int E) {
  int e = blockIdx.x * blockDim.x + threadIdx.x;
  if (e < E) atomicAdd(&counts[dst[e]], 1);
}

__global__ __launch_bounds__(1024) void scan1(const int* __restrict__ counts,
                                              int* __restrict__ row_ptr,
                                              int* __restrict__ bsums, int N) {
  __shared__ int s[1024];
  int t = threadIdx.x;
  int i = blockIdx.x * 1024 + t;
  int v = (i < N) ? counts[i] : 0;
  s[t] = v;
  __syncthreads();
  for (int off = 1; off < 1024; off <<= 1) {
    int u = (t >= off) ? s[t - off] : 0;
    __syncthreads();
    s[t] += u;
    __syncthreads();
  }
  if (i < N) row_ptr[i + 1] = s[t];
  if (t == 1023) bsums[blockIdx.x] = s[1023];
  if (i == 0) row_ptr[0] = 0;
}

__global__ __launch_bounds__(1024) void scan2(int* __restrict__ bsums, int nb) {
  __shared__ int s[1024];
  int t = threadIdx.x;
  int v = (t < nb) ? bsums[t] : 0;
  s[t] = v;
  __syncthreads();
  for (int off = 1; off < 1024; off <<= 1) {
    int u = (t >= off) ? s[t - off] : 0;
    __syncthreads();
    s[t] += u;
    __syncthreads();
  }
  if (t < nb) bsums[t] = (t == 0) ? 0 : s[t - 1];
}

__global__ void scan3(int* __restrict__ row_ptr, const int* __restrict__ bsums, int N) {
  int i = blockIdx.x * blockDim.x + threadIdx.x;
  if (i < N) row_ptr[i + 1] += bsums[i >> 10];
}

__global__ void copy_fill(int* __restrict__ fill, const int* __restrict__ row_ptr, int N) {
  int i = blockIdx.x * blockDim.x + threadIdx.x;
  if (i < N) fill[i] = row_ptr[i];
}

__global__ void fill_col(const int* __restrict__ src, const int* __restrict__ dst,
                         int* __restrict__ fill, int* __restrict__ col,
                         int* __restrict__ eid, int E) {
  int e = blockIdx.x * blockDim.x + threadIdx.x;
  if (e < E) {
    int pos = atomicAdd(&fill[dst[e]], 1);
    col[pos] = src[e];
    eid[pos] = e;
  }
}

__global__ void compute_dinv(const int* __restrict__ counts, float* __restrict__ dinv, int N) {
  int i = blockIdx.x * blockDim.x + threadIdx.x;
  if (i < N) dinv[i] = rsqrtf((float)(counts[i] + 1));
}

// ---------- node encoder: Linear(7->128) + LN + ReLU ----------
__global__ __launch_bounds__(128) void encoder(const float* __restrict__ nf,
                                               const float* __restrict__ enc_w,
                                               const float* __restrict__ enc_b,
                                               const float* __restrict__ g,
                                               const float* __restrict__ bt,
                                               float* __restrict__ x, int N) {
  int n = blockIdx.x;
  int t = threadIdx.x;
  __shared__ float f[7];
  if (t < 7) f[t] = nf[(size_t)n * 7 + t];
  __syncthreads();
  float v = enc_b[t];
  #pragma unroll
  for (int k = 0; k < 7; k++) v = fmaf(f[k], enc_w[k * HD + t], v);
  float s1 = v, s2 = v * v;
  block_reduce2_128(s1, s2);
  float mu = s1 * (1.f / HD);
  float var = s2 * (1.f / HD) - mu * mu;
  float o = (v - mu) * rsqrtf(var + LN_EPS) * g[t] + bt[t];
  x[(size_t)n * HD + t] = fmaxf(o, 0.f);
}

// ---------- GEMM: out_bf16[N,128] = in[N,128] @ W[128,128] ----------
__global__ __launch_bounds__(256) void gemm128(const float* __restrict__ in,
                                               const float* __restrict__ W,
                                               u32* __restrict__ out, int N) {
  __shared__ float Ws[64 * HD];
  __shared__ float xs[32 * HD];
  int t = threadIdx.x;
  int node0 = blockIdx.x * 32;
  for (int i = t; i < 32 * (HD / 4); i += 256) {
    int node = node0 + (i >> 5);
    float4 v = make_float4(0.f, 0.f, 0.f, 0.f);
    if (node < N) v = reinterpret_cast<const float4*>(in)[(size_t)node * (HD / 4) + (i & 31)];
    reinterpret_cast<float4*>(xs)[i] = v;
  }
  int cg = t & 31;   // channels 4*cg..4*cg+3
  int ng = t >> 5;   // nodes   node0+4*ng..+3
  float acc[4][4] = {{0.f}};
  for (int k0 = 0; k0 < HD; k0 += 64) {
    __syncthreads();
    for (int i = t; i < 64 * (HD / 4); i += 256)
      reinterpret_cast<float4*>(Ws)[i] =
          reinterpret_cast<const float4*>(W + (size_t)k0 * HD)[i];
    __syncthreads();
    for (int k = 0; k < 64; k += 4) {
      float4 xv[4];
      #pragma unroll
      for (int nn = 0; nn < 4; nn++)
        xv[nn] = reinterpret_cast<const float4*>(xs + (ng * 4 + nn) * HD)[(k0 + k) >> 2];
      #pragma unroll
      for (int j = 0; j < 4; j++) {
        float4 wv = reinterpret_cast<const float4*>(Ws + (k + j) * HD)[cg];
        #pragma unroll
        for (int nn = 0; nn < 4; nn++) {
          float xe = (j == 0) ? xv[nn].x : (j == 1) ? xv[nn].y : (j == 2) ? xv[nn].z : xv[nn].w;
          acc[nn][0] = fmaf(xe, wv.x, acc[nn][0]);
          acc[nn][1] = fmaf(xe, wv.y, acc[nn][1]);
          acc[nn][2] = fmaf(xe, wv.z, acc[nn][2]);
          acc[nn][3] = fmaf(xe, wv.w, acc[nn][3]);
        }
      }
    }
  }
  #pragma unroll
  for (int nn = 0; nn < 4; nn++) {
    int node = node0 + ng * 4 + nn;
    if (node < N) {
      uint2 pk;
      pk.x = pack2(acc[nn][0], acc[nn][1]);
      pk.y = pack2(acc[nn][2], acc[nn][3]);
      reinterpret_cast<uint2*>(out)[(size_t)node * 32 + cg] = pk;
    }
  }
}

// ---------- fused gather-aggregate + bias + LN + ReLU + residual ----------
// wave per node; lane l owns channels 2l, 2l+1 (bf16x2 dword gathers)
__global__ __launch_bounds__(128) void aggregate(const u32* __restrict__ h,
                                                 const float* __restrict__ xin,
                                                 const int* __restrict__ row_ptr,
                                                 const int* __restrict__ col,
                                                 const float* __restrict__ dinv,
                                                 const float* __restrict__ conv_b,
                                                 const float* __restrict__ g,
                                                 const float* __restrict__ bt,
                                                 float* __restrict__ xout, int N) {
  int n = blockIdx.x * 2 + (threadIdx.x >> 6);
  if (n >= N) return;
  int l = threadIdx.x & 63;
  int beg = row_ptr[n], end = row_ptr[n + 1];
  float dn = dinv[n];
  u32 hv = h[(size_t)n * 64 + l];          // self loop
  float a0 = dn * bf_lo(hv), a1 = dn * bf_hi(hv);
  for (int base = beg; base < end; base += 64) {
    int m = min(64, end - base);
    int s = 0; float dv = 0.f;
    if (l < m) { s = col[base + l]; dv = dinv[s]; }
    int j = 0;
    for (; j + 4 <= m; j += 4) {
      int s0 = __shfl(s, j), s1 = __shfl(s, j + 1), s2 = __shfl(s, j + 2), s3 = __shfl(s, j + 3);
      float d0 = __shfl(dv, j), d1 = __shfl(dv, j + 1), d2 = __shfl(dv, j + 2), d3 = __shfl(dv, j + 3);
      u32 v0 = h[(size_t)s0 * 64 + l];
      u32 v1 = h[(size_t)s1 * 64 + l];
      u32 v2 = h[(size_t)s2 * 64 + l];
      u32 v3 = h[(size_t)s3 * 64 + l];
      a0 = fmaf(d0, bf_lo(v0), a0); a1 = fmaf(d0, bf_hi(v0), a1);
      a0 = fmaf(d1, bf_lo(v1), a0); a1 = fmaf(d1, bf_hi(v1), a1);
      a0 = fmaf(d2, bf_lo(v2), a0); a1 = fmaf(d2, bf_hi(v2), a1);
      a0 = fmaf(d3, bf_lo(v3), a0); a1 = fmaf(d3, bf_hi(v3), a1);
    }
    for (; j < m; j++) {
      int sj = __shfl(s, j);
      float dj = __shfl(dv, j);
      u32 v = h[(size_t)sj * 64 + l];
      a0 = fmaf(dj, bf_lo(v), a0); a1 = fmaf(dj, bf_hi(v), a1);
    }
  }
  float2 bb = reinterpret_cast<const float2*>(conv_b)[l];
  float v0 = dn * a0 + bb.x;
  float v1 = dn * a1 + bb.y;
  float s1 = v0 + v1, s2 = v0 * v0 + v1 * v1;
  #pragma unroll
  for (int off = 32; off > 0; off >>= 1) {
    s1 += __shfl_xor(s1, off);
    s2 += __shfl_xor(s2, off);
  }
  float mu = s1 * (1.f / HD);
  float var = s2 * (1.f / HD) - mu * mu;
  float rs = rsqrtf(var + LN_EPS);
  float2 gg = reinterpret_cast<const float2*>(g)[l];
  float2 bt2 = reinterpret_cast<const float2*>(bt)[l];
  float2 xr = reinterpret_cast<const float2*>(xin)[(size_t)n * 64 + l];
  float o0 = fmaxf((v0 - mu) * rs * gg.x + bt2.x, 0.f) + xr.x;
  float o1 = fmaxf((v1 - mu) * rs * gg.y + bt2.y, 0.f) + xr.y;
  reinterpret_cast<float2*>(xout)[(size_t)n * 64 + l] = make_float2(o0, o1);
}

// ---------- edge scoring, dst-grouped: logit = relu(P[src]+Q[dst]+b1) . W2 + b2 ----------
// wave per dst node; 4 edges / wave iteration; 16 lanes/edge; lane owns 8 channels
__global__ __launch_bounds__(128) void edge_mlp(const u32* __restrict__ P,
                                                const u32* __restrict__ Q,
                                                const int* __restrict__ rowp,
                                                const int* __restrict__ col,
                                                const int* __restrict__ eid,
                                                const float* __restrict__ b1,
                                                const float* __restrict__ w2,
                                                const float* __restrict__ b2,
                                                float* __restrict__ out, int N) {
  int n = blockIdx.x * 2 + (threadIdx.x >> 6);
  if (n >= N) return;
  int l = threadIdx.x & 63;
  int g = l >> 4, li = l & 15;
  int beg = rowp[n], end = rowp[n + 1];
  if (beg == end) return;
  const uint4* P4 = reinterpret_cast<const uint4*>(P);
  uint4 qv = reinterpret_cast<const uint4*>(Q)[(size_t)n * 16 + li];
  float4 bA = reinterpret_cast<const float4*>(b1)[2 * li];
  float4 bB = reinterpret_cast<const float4*>(b1)[2 * li + 1];
  float4 wA = reinterpret_cast<const float4*>(w2)[2 * li];
  float4 wB = reinterpret_cast<const float4*>(w2)[2 * li + 1];
  float q0 = bf_lo(qv.x) + bA.x, q1 = bf_hi(qv.x) + bA.y;
  float q2 = bf_lo(qv.y) + bA.z, q3 = bf_hi(qv.y) + bA.w;
  float q4 = bf_lo(qv.z) + bB.x, q5 = bf_hi(qv.z) + bB.y;
  float q6 = bf_lo(qv.w) + bB.z, q7 = bf_hi(qv.w) + bB.w;
  float b2v = b2[0];
  for (int base = beg; base < end; base += 64) {
    int m = min(64, end - base);
    int s = 0, id = 0;
    if (l < m) { s = col[base + l]; id = eid[base + l]; }
    int nj = (m + 3) >> 2;
    for (int j = 0; j < nj; j++) {
      int ei = j * 4 + g;
      int sj = __shfl(s, ei);
      int idj = __shfl(id, ei);
      float acc = 0.f;
      if (ei < m) {
        uint4 pv = P4[(size_t)sj * 16 + li];
        float hh;
        hh = fmaxf(bf_lo(pv.x) + q0, 0.f); acc = fmaf(hh, wA.x, acc);
        hh = fmaxf(bf_hi(pv.x) + q1, 0.f); acc = fmaf(hh, wA.y, acc);
        hh = fmaxf(bf_lo(pv.y) + q2, 0.f); acc = fmaf(hh, wA.z, acc);
        hh = fmaxf(bf_hi(pv.y) + q3, 0.f); acc = fmaf(hh, wA.w, acc);
        hh = fmaxf(bf_lo(pv.z) + q4, 0.f); acc = fmaf(hh, wB.x, acc);
        hh = fmaxf(bf_hi(pv.z) + q5, 0.f); acc = fmaf(hh, wB.y, acc);
        hh = fmaxf(bf_lo(pv.w) + q6, 0.f); acc = fmaf(hh, wB.z, acc);
        hh = fmaxf(bf_hi(pv.w) + q7, 0.f); acc = fmaf(hh, wB.w, acc);
      }
      acc += __shfl_down(acc, 8, 16);
      acc += __shfl_down(acc, 4, 16);
      acc += __shfl_down(acc, 2, 16);
      acc += __shfl_down(acc, 1, 16);
      if (li == 0 && ei < m) out[idj] = acc + b2v;
    }
  }
}

extern "C" void kernel_launch(void* const* d_in, const int* in_sizes, int n_in,
                              void* d_out, int out_size, void* d_ws, size_t ws_size,
                              hipStream_t stream) {
  const float* node_features = (const float*)d_in[0];
  const int*   edge_index    = (const int*)d_in[1];
  const float* enc_w    = (const float*)d_in[3];
  const float* enc_b    = (const float*)d_in[4];
  const float* enc_ln_g = (const float*)d_in[5];
  const float* enc_ln_b = (const float*)d_in[6];
  const float* conv_w   = (const float*)d_in[7];
  const float* conv_b   = (const float*)d_in[8];
  const float* ln_g     = (const float*)d_in[9];
  const float* ln_b     = (const float*)d_in[10];
  const float* mlp_w1   = (const float*)d_in[11];
  const float* mlp_b1   = (const float*)d_in[12];
  const float* mlp_w2   = (const float*)d_in[13];
  const float* mlp_b2   = (const float*)d_in[14];

  const int N = in_sizes[0] / 7;
  const int E = in_sizes[1] / 2;
  const int* src = edge_index;
  const int* dst = edge_index + E;

  // workspace layout (~117 MB)
  char* ws = (char*)d_ws;
  float* x    = (float*)ws;  ws += (size_t)N * HD * 4;   // fp32 node state
  u32*   h    = (u32*)ws;    ws += (size_t)N * 64 * 4;   // bf16x2 GEMM out / P
  u32*   qb   = (u32*)ws;    ws += (size_t)N * 64 * 4;   // bf16x2 Q
  float* dinv = (float*)ws;  ws += (size_t)N * 4;
  int* counts = (int*)ws;    ws += (size_t)N * 4;
  int* fill   = (int*)ws;    ws += (size_t)N * 4;
  int* col    = (int*)ws;    ws += (size_t)E * 4;
  int* eidp   = (int*)ws;    ws += (size_t)E * 4;
  int* rowp   = (int*)ws;    ws += (size_t)(N + 1) * 4;
  int* bsums  = (int*)ws;    ws += 4096;

  float* out_x      = (float*)d_out;
  float* out_logits = out_x + (size_t)N * HD;

  const int T = 256;
  int nblk = (N + 1023) / 1024;

  // CSR (by dst) + degrees
  init_counts<<<(N + T - 1) / T, T, 0, stream>>>(counts, N);
  count_deg<<<(E + T - 1) / T, T, 0, stream>>>(dst, counts, E);
  scan1<<<nblk, 1024, 0, stream>>>(counts, rowp, bsums, N);
  scan2<<<1, 1024, 0, stream>>>(bsums, nblk);
  scan3<<<(N + T - 1) / T, T, 0, stream>>>(rowp, bsums, N);
  copy_fill<<<(N + T - 1) / T, T, 0, stream>>>(fill, rowp, N);
  fill_col<<<(E + T - 1) / T, T, 0, stream>>>(src, dst, fill, col, eidp, E);
  compute_dinv<<<(N + T - 1) / T, T, 0, stream>>>(counts, dinv, N);

  // encoder
  encoder<<<N, 128, 0, stream>>>(node_features, enc_w, enc_b, enc_ln_g, enc_ln_b, x, N);

  // GCN layers
  int gblk = (N + 31) / 32;
  int ablk = (N + 1) / 2;
  for (int l = 0; l < 3; l++) {
    gemm128<<<gblk, 256, 0, stream>>>(x, conv_w + (size_t)l * HD * HD, h, N);
    float* xout = (l == 2) ? out_x : x;
    aggregate<<<ablk, 128, 0, stream>>>(h, x, rowp, col, dinv,
                                        conv_b + l * HD, ln_g + l * HD, ln_b + l * HD,
                                        xout, N);
  }

  // edge MLP factored: P = x@W1_top, Q = x@W1_bot
  gemm128<<<gblk, 256, 0, stream>>>(out_x, mlp_w1, h, N);             // P (bf16)
  gemm128<<<gblk, 256, 0, stream>>>(out_x, mlp_w1 + HD * HD, qb, N);  // Q (bf16)
  edge_mlp<<<ablk, 128, 0, stream>>>(h, qb, rowp, col, eidp, mlp_b1, mlp_w2, mlp_b2,
                                     out_logits, E > 0 ? N : N);
}

// Round 3
// 746.340 us; speedup vs baseline: 1.7445x; 1.2415x over previous
//
#include <hip/hip_runtime.h>
#include <hip/hip_bf16.h>

#define HD 128
#define LN_EPS 1e-5f
typedef unsigned int u32;
typedef __attribute__((ext_vector_type(8))) short bf16x8;
typedef __attribute__((ext_vector_type(4))) float f32x4;

// ---------- bf16 pack/unpack (bit-level, round-to-nearest-even) ----------
__device__ __forceinline__ u32 f2bf(float f) {
  u32 u = __float_as_uint(f);
  return (u + 0x7FFFu + ((u >> 16) & 1u)) >> 16;
}
__device__ __forceinline__ float bf_lo(u32 p) { return __uint_as_float(p << 16); }
__device__ __forceinline__ float bf_hi(u32 p) { return __uint_as_float(p & 0xFFFF0000u); }
__device__ __forceinline__ u32 pack2(float a, float b) { return f2bf(a) | (f2bf(b) << 16); }

// ---------- block-wide (128 threads = 2 waves) dual reduction ----------
__device__ __forceinline__ void block_reduce2_128(float& a, float& b) {
  #pragma unroll
  for (int off = 32; off > 0; off >>= 1) {
    a += __shfl_down(a, off);
    b += __shfl_down(b, off);
  }
  __shared__ float pa[2], pb[2];
  int w = threadIdx.x >> 6;
  if ((threadIdx.x & 63) == 0) { pa[w] = a; pb[w] = b; }
  __syncthreads();
  a = pa[0] + pa[1];
  b = pb[0] + pb[1];
}

// ---------- CSR build ----------
__global__ void init_counts(int* __restrict__ counts, int N) {
  int i = blockIdx.x * blockDim.x + threadIdx.x;
  if (i < N) counts[i] = 0;
}

__global__ void count_deg(const int* __restrict__ dst, int* __restrict__ counts, int E) {
  int e = blockIdx.x * blockDim.x + threadIdx.x;
  if (e < E) atomicAdd(&counts[dst[e]], 1);
}

__global__ __launch_bounds__(1024) void scan1(const int* __restrict__ counts,
                                              int* __restrict__ row_ptr,
                                              int* __restrict__ bsums, int N) {
  __shared__ int s[1024];
  int t = threadIdx.x;
  int i = blockIdx.x * 1024 + t;
  int v = (i < N) ? counts[i] : 0;
  s[t] = v;
  __syncthreads();
  for (int off = 1; off < 1024; off <<= 1) {
    int u = (t >= off) ? s[t - off] : 0;
    __syncthreads();
    s[t] += u;
    __syncthreads();
  }
  if (i < N) row_ptr[i + 1] = s[t];
  if (t == 1023) bsums[blockIdx.x] = s[1023];
  if (i == 0) row_ptr[0] = 0;
}

__global__ __launch_bounds__(1024) void scan2(int* __restrict__ bsums, int nb) {
  __shared__ int s[1024];
  int t = threadIdx.x;
  int v = (t < nb) ? bsums[t] : 0;
  s[t] = v;
  __syncthreads();
  for (int off = 1; off < 1024; off <<= 1) {
    int u = (t >= off) ? s[t - off] : 0;
    __syncthreads();
    s[t] += u;
    __syncthreads();
  }
  if (t < nb) bsums[t] = (t == 0) ? 0 : s[t - 1];
}

__global__ void scan3(int* __restrict__ row_ptr, const int* __restrict__ bsums, int N) {
  int i = blockIdx.x * blockDim.x + threadIdx.x;
  if (i < N) row_ptr[i + 1] += bsums[i >> 10];
}

__global__ void copy_fill(int* __restrict__ fill, const int* __restrict__ row_ptr, int N) {
  int i = blockIdx.x * blockDim.x + threadIdx.x;
  if (i < N) fill[i] = row_ptr[i];
}

// scatter col (CSR adjacency) + coalesced inverse permutation ipos[e]
__global__ void fill_col(const int* __restrict__ src, const int* __restrict__ dst,
                         int* __restrict__ fill, int* __restrict__ col,
                         int* __restrict__ ipos, int E) {
  int e = blockIdx.x * blockDim.x + threadIdx.x;
  if (e < E) {
    int pos = atomicAdd(&fill[dst[e]], 1);
    col[pos] = src[e];
    ipos[e] = pos;
  }
}

__global__ void compute_dinv(const int* __restrict__ counts, float* __restrict__ dinv, int N) {
  int i = blockIdx.x * blockDim.x + threadIdx.x;
  if (i < N) dinv[i] = rsqrtf((float)(counts[i] + 1));
}

// ---------- weight prep: Wtb[m][n][k] = bf16(Wsrc_m[k][n]), m=0..4 ----------
// m 0..2: conv_w layers; m=3: mlp_w1 top (rows 0..127); m=4: mlp_w1 bottom
__global__ void conv_weights(const float* __restrict__ conv_w,
                             const float* __restrict__ mlp_w1,
                             u32* __restrict__ Wtb) {
  int i = blockIdx.x * 256 + threadIdx.x;   // over 5*128*64 u32 (k-pairs)
  if (i >= 5 * 128 * 64) return;
  int m = i >> 13;           // /8192
  int r = i & 8191;
  int n = r >> 6;
  int k2 = r & 63;
  const float* src = (m < 3) ? conv_w + (size_t)m * HD * HD
                             : mlp_w1 + (size_t)(m - 3) * HD * HD;
  float a = src[(2 * k2) * HD + n];
  float b = src[(2 * k2 + 1) * HD + n];
  Wtb[i] = pack2(a, b);
}

// ---------- node encoder: Linear(7->128) + LN + ReLU; writes fp32 x + bf16 xb ----------
__global__ __launch_bounds__(128) void encoder(const float* __restrict__ nf,
                                               const float* __restrict__ enc_w,
                                               const float* __restrict__ enc_b,
                                               const float* __restrict__ g,
                                               const float* __restrict__ bt,
                                               float* __restrict__ x,
                                               u32* __restrict__ xb, int N) {
  int n = blockIdx.x;
  int t = threadIdx.x;
  __shared__ float f[7];
  if (t < 7) f[t] = nf[(size_t)n * 7 + t];
  __syncthreads();
  float v = enc_b[t];
  #pragma unroll
  for (int k = 0; k < 7; k++) v = fmaf(f[k], enc_w[k * HD + t], v);
  float s1 = v, s2 = v * v;
  block_reduce2_128(s1, s2);
  float mu = s1 * (1.f / HD);
  float var = s2 * (1.f / HD) - mu * mu;
  float o = fmaxf((v - mu) * rsqrtf(var + LN_EPS) * g[t] + bt[t], 0.f);
  x[(size_t)n * HD + t] = o;
  float o2 = __shfl_down(o, 1);
  if ((t & 1) == 0) xb[(size_t)n * 64 + (t >> 1)] = pack2(o, o2);
}

// ---------- MFMA GEMM: h[N,128]bf16 = xb[N,128]bf16 @ W  (W given as Wt[n][k] bf16) ----------
// block 256 thr = 4 waves; M-tile 64 rows; wave w owns rows w*16..+15, all 128 cols.
__global__ __launch_bounds__(256) void gemm_mfma(const u32* __restrict__ xb,
                                                 const u32* __restrict__ Wt,
                                                 u32* __restrict__ h, int N) {
  __shared__ u32 lds[8192];   // 32 KB: phase 1 = swizzled Wt; phase 2 = C tile
  int t = threadIdx.x;
  int node0 = blockIdx.x * 64;
  // stage Wt with XOR swizzle on 16B chunks: chunk kc of row n -> slot kc ^ (n&15)
  {
    uint4* l4 = reinterpret_cast<uint4*>(lds);
    const uint4* s4 = reinterpret_cast<const uint4*>(Wt);
    for (int i = t; i < 2048; i += 256) {
      int n = i >> 4, kc = i & 15;
      l4[(n << 4) + (kc ^ (n & 15))] = s4[i];
    }
  }
  int w = t >> 6, l = t & 63;
  int m15 = l & 15, kq = l >> 4;
  int grow = node0 + w * 16 + m15;
  bf16x8 afrag[4];
  bool rowok = grow < N;
  #pragma unroll
  for (int c = 0; c < 4; c++) {
    if (rowok)
      afrag[c] = *reinterpret_cast<const bf16x8*>(
          reinterpret_cast<const short*>(xb) + (size_t)grow * HD + c * 32 + kq * 8);
    else
      afrag[c] = bf16x8{0, 0, 0, 0, 0, 0, 0, 0};
  }
  __syncthreads();
  f32x4 acc[8];
  #pragma unroll
  for (int tl = 0; tl < 8; tl++) acc[tl] = f32x4{0.f, 0.f, 0.f, 0.f};
  const uint4* l4 = reinterpret_cast<const uint4*>(lds);
  #pragma unroll
  for (int tl = 0; tl < 8; tl++) {
    int n = tl * 16 + m15;
    #pragma unroll
    for (int c = 0; c < 4; c++) {
      bf16x8 bfrag = *reinterpret_cast<const bf16x8*>(&l4[(n << 4) + ((c * 4 + kq) ^ (n & 15))]);
      acc[tl] = __builtin_amdgcn_mfma_f32_16x16x32_bf16(afrag[c], bfrag, acc[tl], 0, 0, 0);
    }
  }
  __syncthreads();
  // C: lane holds col=tl*16+m15, rows w*16 + kq*4 + r. Stage to LDS (stride 136 shorts).
  short* cs = reinterpret_cast<short*>(lds);
  #pragma unroll
  for (int tl = 0; tl < 8; tl++) {
    int colc = tl * 16 + m15;
    #pragma unroll
    for (int r = 0; r < 4; r++)
      cs[(w * 16 + kq * 4 + r) * 136 + colc] = (short)f2bf(acc[tl][r]);
  }
  __syncthreads();
  for (int i = t; i < 1024; i += 256) {   // 64 rows x 16 uint4
    int row = i >> 4;
    int node = node0 + row;
    if (node < N) {
      uint4 v = *reinterpret_cast<const uint4*>(&lds[row * 68 + (i & 15) * 4]);
      reinterpret_cast<uint4*>(h)[(size_t)node * 16 + (i & 15)] = v;
    }
  }
}

// ---------- fused gather-aggregate + bias + LN + ReLU + residual ----------
// wave per node; lane l owns channels 2l, 2l+1; writes fp32 xout + bf16 xb
__global__ __launch_bounds__(128) void aggregate(const u32* __restrict__ h,
                                                 const float* __restrict__ xin,
                                                 const int* __restrict__ row_ptr,
                                                 const int* __restrict__ col,
                                                 const float* __restrict__ dinv,
                                                 const float* __restrict__ conv_b,
                                                 const float* __restrict__ g,
                                                 const float* __restrict__ bt,
                                                 float* __restrict__ xout,
                                                 u32* __restrict__ xb, int N) {
  int n = blockIdx.x * 2 + (threadIdx.x >> 6);
  if (n >= N) return;
  int l = threadIdx.x & 63;
  int beg = row_ptr[n], end = row_ptr[n + 1];
  float dn = dinv[n];
  u32 hv = h[(size_t)n * 64 + l];
  float a0 = dn * bf_lo(hv), a1 = dn * bf_hi(hv);
  for (int base = beg; base < end; base += 64) {
    int m = min(64, end - base);
    int s = 0; float dv = 0.f;
    if (l < m) { s = col[base + l]; dv = dinv[s]; }
    int j = 0;
    for (; j + 4 <= m; j += 4) {
      int s0 = __shfl(s, j), s1 = __shfl(s, j + 1), s2 = __shfl(s, j + 2), s3 = __shfl(s, j + 3);
      float d0 = __shfl(dv, j), d1 = __shfl(dv, j + 1), d2 = __shfl(dv, j + 2), d3 = __shfl(dv, j + 3);
      u32 v0 = h[(size_t)s0 * 64 + l];
      u32 v1 = h[(size_t)s1 * 64 + l];
      u32 v2 = h[(size_t)s2 * 64 + l];
      u32 v3 = h[(size_t)s3 * 64 + l];
      a0 = fmaf(d0, bf_lo(v0), a0); a1 = fmaf(d0, bf_hi(v0), a1);
      a0 = fmaf(d1, bf_lo(v1), a0); a1 = fmaf(d1, bf_hi(v1), a1);
      a0 = fmaf(d2, bf_lo(v2), a0); a1 = fmaf(d2, bf_hi(v2), a1);
      a0 = fmaf(d3, bf_lo(v3), a0); a1 = fmaf(d3, bf_hi(v3), a1);
    }
    for (; j < m; j++) {
      int sj = __shfl(s, j);
      float dj = __shfl(dv, j);
      u32 v = h[(size_t)sj * 64 + l];
      a0 = fmaf(dj, bf_lo(v), a0); a1 = fmaf(dj, bf_hi(v), a1);
    }
  }
  float2 bb = reinterpret_cast<const float2*>(conv_b)[l];
  float v0 = dn * a0 + bb.x;
  float v1 = dn * a1 + bb.y;
  float s1 = v0 + v1, s2 = v0 * v0 + v1 * v1;
  #pragma unroll
  for (int off = 32; off > 0; off >>= 1) {
    s1 += __shfl_xor(s1, off);
    s2 += __shfl_xor(s2, off);
  }
  float mu = s1 * (1.f / HD);
  float var = s2 * (1.f / HD) - mu * mu;
  float rs = rsqrtf(var + LN_EPS);
  float2 gg = reinterpret_cast<const float2*>(g)[l];
  float2 bt2 = reinterpret_cast<const float2*>(bt)[l];
  float2 xr = reinterpret_cast<const float2*>(xin)[(size_t)n * 64 + l];
  float o0 = fmaxf((v0 - mu) * rs * gg.x + bt2.x, 0.f) + xr.x;
  float o1 = fmaxf((v1 - mu) * rs * gg.y + bt2.y, 0.f) + xr.y;
  reinterpret_cast<float2*>(xout)[(size_t)n * 64 + l] = make_float2(o0, o1);
  xb[(size_t)n * 64 + l] = pack2(o0, o1);
}

// ---------- edge scoring, dst-grouped; writes logits in CSR order (coalesced) ----------
__global__ __launch_bounds__(128) void edge_mlp(const u32* __restrict__ P,
                                                const u32* __restrict__ Q,
                                                const int* __restrict__ rowp,
                                                const int* __restrict__ col,
                                                const float* __restrict__ b1,
                                                const float* __restrict__ w2,
                                                const float* __restrict__ b2,
                                                float* __restrict__ tmp, int N) {
  int n = blockIdx.x * 2 + (threadIdx.x >> 6);
  if (n >= N) return;
  int l = threadIdx.x & 63;
  int g = l >> 4, li = l & 15;
  int beg = rowp[n], end = rowp[n + 1];
  if (beg == end) return;
  const uint4* P4 = reinterpret_cast<const uint4*>(P);
  uint4 qv = reinterpret_cast<const uint4*>(Q)[(size_t)n * 16 + li];
  float4 bA = reinterpret_cast<const float4*>(b1)[2 * li];
  float4 bB = reinterpret_cast<const float4*>(b1)[2 * li + 1];
  float4 wA = reinterpret_cast<const float4*>(w2)[2 * li];
  float4 wB = reinterpret_cast<const float4*>(w2)[2 * li + 1];
  float q0 = bf_lo(qv.x) + bA.x, q1 = bf_hi(qv.x) + bA.y;
  float q2 = bf_lo(qv.y) + bA.z, q3 = bf_hi(qv.y) + bA.w;
  float q4 = bf_lo(qv.z) + bB.x, q5 = bf_hi(qv.z) + bB.y;
  float q6 = bf_lo(qv.w) + bB.z, q7 = bf_hi(qv.w) + bB.w;
  float b2v = b2[0];
  for (int base = beg; base < end; base += 64) {
    int m = min(64, end - base);
    int s = 0;
    if (l < m) s = col[base + l];
    int nj = (m + 3) >> 2;
    for (int j = 0; j < nj; j++) {
      int ei = j * 4 + g;
      int sj = __shfl(s, ei);
      float acc = 0.f;
      if (ei < m) {
        uint4 pv = P4[(size_t)sj * 16 + li];
        float hh;
        hh = fmaxf(bf_lo(pv.x) + q0, 0.f); acc = fmaf(hh, wA.x, acc);
        hh = fmaxf(bf_hi(pv.x) + q1, 0.f); acc = fmaf(hh, wA.y, acc);
        hh = fmaxf(bf_lo(pv.y) + q2, 0.f); acc = fmaf(hh, wA.z, acc);
        hh = fmaxf(bf_hi(pv.y) + q3, 0.f); acc = fmaf(hh, wA.w, acc);
        hh = fmaxf(bf_lo(pv.z) + q4, 0.f); acc = fmaf(hh, wB.x, acc);
        hh = fmaxf(bf_hi(pv.z) + q5, 0.f); acc = fmaf(hh, wB.y, acc);
        hh = fmaxf(bf_lo(pv.w) + q6, 0.f); acc = fmaf(hh, wB.z, acc);
        hh = fmaxf(bf_hi(pv.w) + q7, 0.f); acc = fmaf(hh, wB.w, acc);
      }
      acc += __shfl_down(acc, 8, 16);
      acc += __shfl_down(acc, 4, 16);
      acc += __shfl_down(acc, 2, 16);
      acc += __shfl_down(acc, 1, 16);
      if (li == 0 && ei < m) tmp[base + ei] = acc + b2v;
    }
  }
}

// ---------- final permute: out[e] = tmp[ipos[e]] (random reads from L2-resident tmp) ----------
__global__ void permute_out(const float* __restrict__ tmp, const int* __restrict__ ipos,
                            float* __restrict__ out, int E) {
  int e = blockIdx.x * blockDim.x + threadIdx.x;
  if (e < E) out[e] = tmp[ipos[e]];
}

extern "C" void kernel_launch(void* const* d_in, const int* in_sizes, int n_in,
                              void* d_out, int out_size, void* d_ws, size_t ws_size,
                              hipStream_t stream) {
  const float* node_features = (const float*)d_in[0];
  const int*   edge_index    = (const int*)d_in[1];
  const float* enc_w    = (const float*)d_in[3];
  const float* enc_b    = (const float*)d_in[4];
  const float* enc_ln_g = (const float*)d_in[5];
  const float* enc_ln_b = (const float*)d_in[6];
  const float* conv_w   = (const float*)d_in[7];
  const float* conv_b   = (const float*)d_in[8];
  const float* ln_g     = (const float*)d_in[9];
  const float* ln_b     = (const float*)d_in[10];
  const float* mlp_w1   = (const float*)d_in[11];
  const float* mlp_b1   = (const float*)d_in[12];
  const float* mlp_w2   = (const float*)d_in[13];
  const float* mlp_b2   = (const float*)d_in[14];

  const int N = in_sizes[0] / 7;
  const int E = in_sizes[1] / 2;
  const int* src = edge_index;
  const int* dst = edge_index + E;

  // workspace layout (~137 MB); tmp aliases x (x dead when edge_mlp runs)
  char* ws = (char*)d_ws;
  float* x    = (float*)ws;  ws += (size_t)N * HD * 4;   // fp32 node state
  u32*   h    = (u32*)ws;    ws += (size_t)N * 64 * 4;   // bf16x2 GEMM out / P
  u32*   qb   = (u32*)ws;    ws += (size_t)N * 64 * 4;   // bf16x2 Q
  u32*   xb   = (u32*)ws;    ws += (size_t)N * 64 * 4;   // bf16x2 shadow of x
  u32*   Wtb  = (u32*)ws;    ws += (size_t)5 * 128 * 64 * 4;
  float* dinv = (float*)ws;  ws += (size_t)N * 4;
  int* counts = (int*)ws;    ws += (size_t)N * 4;
  int* fill   = (int*)ws;    ws += (size_t)N * 4;
  int* col    = (int*)ws;    ws += (size_t)E * 4;
  int* ipos   = (int*)ws;    ws += (size_t)E * 4;
  int* rowp   = (int*)ws;    ws += (size_t)(N + 1) * 4;
  int* bsums  = (int*)ws;    ws += 4096;
  float* tmp  = x;                                        // alias: E <= N*HD

  float* out_x      = (float*)d_out;
  float* out_logits = out_x + (size_t)N * HD;

  const int T = 256;
  int nblk = (N + 1023) / 1024;

  // CSR (by dst) + degrees
  init_counts<<<(N + T - 1) / T, T, 0, stream>>>(counts, N);
  count_deg<<<(E + T - 1) / T, T, 0, stream>>>(dst, counts, E);
  scan1<<<nblk, 1024, 0, stream>>>(counts, rowp, bsums, N);
  scan2<<<1, 1024, 0, stream>>>(bsums, nblk);
  scan3<<<(N + T - 1) / T, T, 0, stream>>>(rowp, bsums, N);
  copy_fill<<<(N + T - 1) / T, T, 0, stream>>>(fill, rowp, N);
  fill_col<<<(E + T - 1) / T, T, 0, stream>>>(src, dst, fill, col, ipos, E);
  compute_dinv<<<(N + T - 1) / T, T, 0, stream>>>(counts, dinv, N);

  // weights: transpose + bf16
  conv_weights<<<(5 * 128 * 64 + T - 1) / T, T, 0, stream>>>(conv_w, mlp_w1, Wtb);

  // encoder
  encoder<<<N, 128, 0, stream>>>(node_features, enc_w, enc_b, enc_ln_g, enc_ln_b, x, xb, N);

  // GCN layers (MFMA GEMM + fused aggregate)
  int gblk = (N + 63) / 64;
  int ablk = (N + 1) / 2;
  for (int l = 0; l < 3; l++) {
    gemm_mfma<<<gblk, 256, 0, stream>>>(xb, Wtb + (size_t)l * 8192, h, N);
    float* xout = (l == 2) ? out_x : x;
    aggregate<<<ablk, 128, 0, stream>>>(h, x, rowp, col, dinv,
                                        conv_b + l * HD, ln_g + l * HD, ln_b + l * HD,
                                        xout, xb, N);
  }

  // edge MLP factored: P = x@W1_top, Q = x@W1_bot (from bf16 shadow of final x)
  gemm_mfma<<<gblk, 256, 0, stream>>>(xb, Wtb + (size_t)3 * 8192, h, N);   // P
  gemm_mfma<<<gblk, 256, 0, stream>>>(xb, Wtb + (size_t)4 * 8192, qb, N);  // Q
  edge_mlp<<<ablk, 128, 0, stream>>>(h, qb, rowp, col, mlp_b1, mlp_w2, mlp_b2, tmp, N);
  permute_out<<<(E + T - 1) / T, T, 0, stream>>>(tmp, ipos, out_logits, E);
}